// Round 8
// baseline (274.953 us; speedup 1.0000x reference)
//
#include <hip/hip_runtime.h>

#define K_DIM 8192
#define M_REAL 2000
#define N_REAL 2000
#define M_PAD 2048
#define N_PAD 2048

#define BM 256
#define BN 256
#define BK 32
#define SPLITK 4
#define KSLAB (K_DIM / SPLITK)   // 2048
#define NIT (KSLAB / BK)         // 64

// prep: grid-stride phases (few blocks, more work per block)
#define PW_BLOCKS 2048           // W convert: 4 sweeps x 8 elems/thread
#define PX_BLOCKS 1024           // X transpose: 4 tiles/block
#define PB_BLOCKS 128            // bias prefill: grid-stride

typedef __bf16 bf16x8 __attribute__((ext_vector_type(8)));
typedef float f32x4 __attribute__((ext_vector_type(4)));
typedef float fvec4 __attribute__((ext_vector_type(4)));
typedef unsigned short us8v __attribute__((ext_vector_type(8)));

#define RAW_BARRIER()  asm volatile("s_barrier" ::: "memory")
#define WAIT_VM4()     asm volatile("s_waitcnt vmcnt(4)" ::: "memory")
#define WAIT_VM0()     asm volatile("s_waitcnt vmcnt(0)" ::: "memory")

__device__ __forceinline__ unsigned short f2bf(float f) {
    union { float f; unsigned u; } v; v.f = f;
    unsigned r = v.u + 0x7FFFu + ((v.u >> 16) & 1u);  // RNE; inputs are finite normals
    return (unsigned short)(r >> 16);
}

__device__ __forceinline__ void async16(const void* g, void* l) {
    __builtin_amdgcn_global_load_lds((__attribute__((address_space(1))) void*)(g),
                                     (__attribute__((address_space(3))) void*)(l),
                                     16, 0, 0);
}

// ---------------------------------------------------------------------------
// Fused prep, grid-strided (3200 blocks total vs 24387 before — tests the
// dispatch-rate theory for prep's 143us):
//   [0, PW_BLOCKS)      W f32 -> Wb bf16 [2048][8192]; 4 sweeps, 8 elem/thread
//   [+PX_BLOCKS)        X [8192][2000] f32 -> XT bf16 [2048][8192]; 4 tiles/blk
//   [+PB_BLOCKS)        out[m][n] = bias[n]; grid-stride
__global__ __launch_bounds__(256) void prep_kernel(const float* __restrict__ W,
                                                   const float* __restrict__ X,
                                                   const float* __restrict__ bias,
                                                   unsigned short* __restrict__ Wb,
                                                   unsigned short* __restrict__ XT,
                                                   float* __restrict__ out) {
    __shared__ unsigned short tile[64][68];
    int bid = blockIdx.x;
    if (bid < PW_BLOCKS) {
        long long tbase = (long long)bid * 256 + threadIdx.x;
#pragma unroll
        for (int it = 0; it < 4; ++it) {
            long long e = (tbase + (long long)it * (PW_BLOCKS * 256)) * 8;
            int m = (int)(e >> 13);
            us8v o = {0, 0, 0, 0, 0, 0, 0, 0};
            if (m < M_REAL) {
                fvec4 f0 = *(const fvec4*)(W + e);
                fvec4 f1 = *(const fvec4*)(W + e + 4);
                o[0] = f2bf(f0.x); o[1] = f2bf(f0.y); o[2] = f2bf(f0.z); o[3] = f2bf(f0.w);
                o[4] = f2bf(f1.x); o[5] = f2bf(f1.y); o[6] = f2bf(f1.z); o[7] = f2bf(f1.w);
            }
            *(us8v*)(Wb + e) = o;
        }
    } else if (bid < PW_BLOCKS + PX_BLOCKS) {
        int b2 = bid - PW_BLOCKS;
        int t = threadIdx.x;
        int c16 = t & 15, r16 = t >> 4;
#pragma unroll
        for (int tit = 0; tit < 4; ++tit) {
            int tid = b2 + tit * PX_BLOCKS;    // 0..4095
            int k0 = (tid & 127) * 64;
            int n0 = (tid >> 7) * 64;
#pragma unroll
            for (int it = 0; it < 4; ++it) {
                int k = k0 + r16 + it * 16;
                int n = n0 + c16 * 4;
                fvec4 v = {0.f, 0.f, 0.f, 0.f};
                if (n < N_REAL)
                    v = *(const fvec4*)(X + (long long)k * N_REAL + n);
                ushort4 o;
                o.x = f2bf(v.x); o.y = f2bf(v.y); o.z = f2bf(v.z); o.w = f2bf(v.w);
                *(ushort4*)&tile[r16 + it * 16][c16 * 4] = o;
            }
            __syncthreads();
#pragma unroll
            for (int it = 0; it < 4; ++it) {
                int nn = r16 + it * 16;           // n - n0
                int k4 = c16 * 4;
                ushort4 o;
                o.x = tile[k4 + 0][nn];
                o.y = tile[k4 + 1][nn];
                o.z = tile[k4 + 2][nn];
                o.w = tile[k4 + 3][nn];
                *(ushort4*)(XT + (long long)(n0 + nn) * K_DIM + k0 + k4) = o;
            }
            __syncthreads();   // protect tile before next sweep's writes
        }
    } else {
        int b3 = bid - PW_BLOCKS - PX_BLOCKS;
        for (int t = b3 * 256 + threadIdx.x; t < M_REAL * (N_REAL / 4); t += PB_BLOCKS * 256) {
            int m = t / (N_REAL / 4);
            int n4 = t - m * (N_REAL / 4);
            float4 bv = *(const float4*)(bias + n4 * 4);
            *(float4*)(out + (long long)m * N_REAL + n4 * 4) = bv;
        }
    }
}

// ---------------------------------------------------------------------------
// Split-K GEMM, 256x256 tile, BK=32, double-buffered LDS with raw s_barrier +
// vmcnt(4). 8 waves x (8x4 MFMA 16x16x32). XCD swizzle: f&7 round-robin.
// Reverted to round-4-exact (round-7 XOR swizzle proven no-op: conflict
// counter bit-identical — the 4 cyc/b128 is structural, not addressing).
__global__ __launch_bounds__(512, 2) void gemm_kernel(const unsigned short* __restrict__ Wb,
                                                      const unsigned short* __restrict__ XT,
                                                      float* __restrict__ out) {
    __shared__ __align__(16) unsigned short As[2][BM * BK];  // 2 x 16 KB
    __shared__ __align__(16) unsigned short Bs[2][BN * BK];  // 2 x 16 KB

    int f = blockIdx.x;
    int xcd = f & 7;
    int local = f >> 3;                    // 0..31
    int bz = local & 3;
    int bx = (xcd & 3) * 2 + ((local >> 2) & 1);   // 0..7
    int by = (xcd >> 2) * 4 + (local >> 3);        // 0..7

    int t = threadIdx.x;
    int w = t >> 6;              // 0..7
    int l = t & 63;
    int wm = (w >> 2) * 128;     // 0 or 128
    int wn = (w & 3) * 64;       // 0,64,128,192
    int lane16 = l & 15;
    int quad = l >> 4;
    int m0 = by * BM;
    int n0 = bx * BN;
    int ks = bz * KSLAB;

    f32x4 acc[8][4] = {};

    int srow = l >> 2;
    int scol = (l & 3) * 8;
    int rb = w * 32;
    const unsigned short* gA0 = Wb + (long long)(m0 + rb + srow) * K_DIM + ks + scol;
    const unsigned short* gA1 = gA0 + 16LL * K_DIM;
    const unsigned short* gB0 = XT + (long long)(n0 + rb + srow) * K_DIM + ks + scol;
    const unsigned short* gB1 = gB0 + 16LL * K_DIM;

    async16(gA0, &As[0][rb * BK]);
    async16(gA1, &As[0][(rb + 16) * BK]);
    async16(gB0, &Bs[0][rb * BK]);
    async16(gB1, &Bs[0][(rb + 16) * BK]);
    gA0 += BK; gA1 += BK; gB0 += BK; gB1 += BK;

    for (int kt = 0; kt < NIT; ++kt) {
        int cur = kt & 1;
        if (kt + 1 < NIT) {
            int nxt = cur ^ 1;
            async16(gA0, &As[nxt][rb * BK]);
            async16(gA1, &As[nxt][(rb + 16) * BK]);
            async16(gB0, &Bs[nxt][rb * BK]);
            async16(gB1, &Bs[nxt][(rb + 16) * BK]);
            gA0 += BK; gA1 += BK; gB0 += BK; gB1 += BK;
            WAIT_VM4();
        } else {
            WAIT_VM0();
        }
        RAW_BARRIER();

        bf16x8 a[8], b[4];
#pragma unroll
        for (int i = 0; i < 8; ++i)
            a[i] = *(const bf16x8*)&As[cur][(wm + i * 16 + lane16) * BK + quad * 8];
#pragma unroll
        for (int j = 0; j < 4; ++j)
            b[j] = *(const bf16x8*)&Bs[cur][(wn + j * 16 + lane16) * BK + quad * 8];

#pragma unroll
        for (int i = 0; i < 8; ++i)
#pragma unroll
            for (int j = 0; j < 4; ++j)
                acc[i][j] = __builtin_amdgcn_mfma_f32_16x16x32_bf16(a[i], b[j], acc[i][j], 0, 0, 0);

        if (kt + 1 < NIT)
            RAW_BARRIER();
    }

    // Epilogue: C/D layout col = lane&15, row = quad*4 + reg  [m89-verified]
#pragma unroll
    for (int j = 0; j < 4; ++j) {
        int n = n0 + wn + j * 16 + lane16;
        if (n >= N_REAL) continue;
#pragma unroll
        for (int i = 0; i < 8; ++i) {
            int mbase = m0 + wm + i * 16 + quad * 4;
#pragma unroll
            for (int r = 0; r < 4; ++r) {
                int m = mbase + r;
                if (m < M_REAL)
                    atomicAdd(&out[(long long)m * N_REAL + n], acc[i][j][r]);
            }
        }
    }
}

// ---------------------------------------------------------------------------
extern "C" void kernel_launch(void* const* d_in, const int* in_sizes, int n_in,
                              void* d_out, int out_size, void* d_ws, size_t ws_size,
                              hipStream_t stream) {
    const float* W    = (const float*)d_in[0];  // [2000][8192]
    const float* bias = (const float*)d_in[1];  // [2000]
    const float* X    = (const float*)d_in[2];  // [8192][2000]
    float* out = (float*)d_out;

    unsigned short* Wb = (unsigned short*)d_ws;                 // [2048][8192] bf16
    unsigned short* XT = Wb + (long long)M_PAD * K_DIM;         // [2048][8192] bf16

    prep_kernel<<<PW_BLOCKS + PX_BLOCKS + PB_BLOCKS, 256, 0, stream>>>(W, X, bias, Wb, XT, out);

    gemm_kernel<<<(N_PAD / BN) * (M_PAD / BM) * SPLITK, 512, 0, stream>>>(Wb, XT, out);
}